// Round 14
// baseline (78.326 us; speedup 1.0000x reference)
//
#include <hip/hip_runtime.h>
#include <hip/hip_bf16.h>
#include <math.h>

// SlowROIPool: adaptive 7x7 max-pool over integer ROI crops.
// images [N=4,C=256,H=50,W=50] f32, rois [R=256,4] f32, roi_idx [R] i32.
// out [R,C,7,7] f32.
//
// R13 lesson (budget finally closes): ~19 us kernel = L1-line path ~7us
// (staging touches ~25 lines/plane incl. clamped-DUP row reloads) + DS ~5
// + VALU ~3 + stores/latency tails. R14 cuts the two residual wastes:
//  (1) dup-row loads/writes removed via per-q exec mask act[q] =
//      stager && (4q+r4 < sh). Valid taps only read rows hs+a <= he-1
//      <= sh-1, so skipped LDS cells are never read (safe).
//  (2) 8 planes per wave (two sequential R13 bodies): waves 16384->8192,
//      per-wave setup (rois scalar load + box/bin/tap math) amortized 2x.
// Everything else identical to the verified R13: float2 staging from even
// x1a ([x1a,x1a+32) always in-row), class-templated Q/A/B, unclamped
// const-delta taps + cndmask, single-buffered pairs (same-wave DS order).
// All indices clamped: no global/LDS access can leave its buffer even under
// transiently-poisoned inputs.

#define S 7
#define NN 4
#define NC 256
#define NH 50
#define NW 50
#define PLANE (NH * NW)   // 2500
#define PITCH 34          // even (float2 align); > 31
#define PROWS 24          // padded rows
#define PBUF (PROWS * PITCH)  // 816 floats per plane buffer
#define WPB 4             // waves per block
#define NINF (-__builtin_huge_valf())

template <int A, int B>
__device__ __forceinline__ float tapmax(const float* __restrict__ L,
                                        int vb, int dh, int dw)
{
    float m = NINF;
#pragma unroll
    for (int a = 0; a < A; ++a) {
#pragma unroll
        for (int b = 0; b < B; ++b) {
            const bool valid = (a < dh) & (b < dw);   // dh<=A, dw<=B by class
            const float x = L[vb + a * PITCH + b];    // in padded buffer
            m = fmaxf(m, valid ? x : NINF);
        }
    }
    return m;
}

// 4-plane body (verified R13 path + dup-row exec masking)
template <int Q, int A, int B>
__device__ __forceinline__ void wave_body(
    const float* __restrict__ gb,    // plane0 base + y1*NW + x1a + 2*w2
    float* __restrict__ L0, float* __restrict__ L1,
    int sh, int r4, int vb, int dh, int dw, int slotbase,
    bool stager, bool computer, float* __restrict__ m)
{
    bool act[Q];
#pragma unroll
    for (int q = 0; q < Q; ++q)
        act[q] = stager && ((4 * q + r4) < sh);   // real rows only

    float2 v[4][Q];
#pragma unroll
    for (int p = 0; p < 4; ++p) {
#pragma unroll
        for (int q = 0; q < Q; ++q) {
            if (act[q])   // rows < sh <= NH-y1: address always in-plane
                v[p][q] = *(const float2*)(gb + (size_t)p * PLANE
                                              + (4 * q + r4) * NW);
        }
    }
#pragma unroll
    for (int q = 0; q < Q; ++q) {
        if (act[q]) {
            const int slot = slotbase + q * 4 * PITCH;    // 8B-aligned
            *(float2*)(L0 + slot) = v[0][q];
            *(float2*)(L1 + slot) = v[1][q];
        }
    }
    if (computer) {
        m[0] = tapmax<A, B>(L0, vb, dh, dw);
        m[1] = tapmax<A, B>(L1, vb, dh, dw);
    }
#pragma unroll
    for (int q = 0; q < Q; ++q) {        // same-wave DS in-order: WAR safe
        if (act[q]) {
            const int slot = slotbase + q * 4 * PITCH;
            *(float2*)(L0 + slot) = v[2][q];
            *(float2*)(L1 + slot) = v[3][q];
        }
    }
    if (computer) {
        m[2] = tapmax<A, B>(L0, vb, dh, dw);
        m[3] = tapmax<A, B>(L1, vb, dh, dw);
    }
}

// 8-plane wrapper: two sequential 4-plane bodies (setup amortized)
template <int Q, int A, int B>
__device__ __forceinline__ void wave_body8(
    const float* __restrict__ gb,
    float* __restrict__ L0, float* __restrict__ L1,
    int sh, int r4, int vb, int dh, int dw, int slotbase,
    bool stager, bool computer, float* __restrict__ m)
{
    wave_body<Q, A, B>(gb, L0, L1, sh, r4, vb, dh, dw, slotbase,
                       stager, computer, m);
    wave_body<Q, A, B>(gb + 4 * (size_t)PLANE, L0, L1, sh, r4, vb, dh, dw,
                       slotbase, stager, computer, m + 4);
}

__global__ __launch_bounds__(256, 4) void roipool_kernel(
    const float* __restrict__ images,
    const float* __restrict__ rois,
    const int* __restrict__ roi_idx,
    float* __restrict__ out,
    int out_size)
{
    __shared__ float lds[WPB][2][PBUF];   // 26.1 KB

    const int t    = threadIdx.x;
    const int wid  = __builtin_amdgcn_readfirstlane(t >> 6);
    const int lane = t & 63;
    const int grp  = blockIdx.x * WPB + wid;   // 8-plane group, < 8192
    int r = __builtin_amdgcn_readfirstlane(grp >> 5);   // 32 groups per ROI
    r = min(max(r, 0), 255);
    const int c0 = (grp & 31) * 8;

    // ---- box math: scalar, clamped (identity on sane inputs) ----
    const float rx1 = rois[4 * r + 0];
    const float ry1 = rois[4 * r + 1];
    const float rx2 = rois[4 * r + 2];
    const float ry2 = rois[4 * r + 3];
    int x1 = __builtin_amdgcn_readfirstlane((int)floorf(rx1 * (float)NW));
    int y1 = __builtin_amdgcn_readfirstlane((int)floorf(ry1 * (float)NH));
    int x2 = __builtin_amdgcn_readfirstlane((int)ceilf(rx2 * (float)NW));
    int y2 = __builtin_amdgcn_readfirstlane((int)ceilf(ry2 * (float)NH));
    x1 = min(max(x1, 0), NW - 1);
    y1 = min(max(y1, 0), NH - 1);
    x2 = min(max(x2, x1 + 1), NW);
    y2 = min(max(y2, y1 + 1), NH);
    const int sw = min(x2 - x1, 22);     // identity on real data (<= 22)
    const int sh = min(y2 - y1, 22);     // y1 + sh <= y2 <= NH: rows in-plane

    int n = __builtin_amdgcn_readfirstlane(roi_idx[r]);
    n = min(max(n, 0), NN - 1);

    // staged window: even start, [x1a, x1a+32) always inside the 50-col row
    const int x1a   = min(x1 & ~1, NW - 32);   // 0..18, even
    const int shift = x1 - x1a;                // 0..31; shift+sw <= 32

    // ---- per-lane bin (lanes 49..63 clone lane 48; masked in tap phase) ----
    const int l  = min(lane, S * S - 1);
    const int i  = l / S;
    const int j  = l - i * S;
    const int hs = (i * sh) / S;
    const int he = ((i + 1) * sh + S - 1) / S;
    const int ws = (j * sw) / S;
    const int we = ((j + 1) * sw + S - 1) / S;
    const int dh = he - hs;                    // <= SP(sh)
    const int dw = we - ws;                    // <= SP(sw)
    const int vb = hs * PITCH + ws + shift;    // max read 766 < 816 (padded)

    // ---- staging lane roles: 4 rows x 16 float2 cols, masked to wpc ----
    const int r4 = lane >> 4;                  // 0..3
    const int w2 = lane & 15;                  // 0..15
    const int wpc = (shift + sw + 1) >> 1;     // needed pairs, 1..16
    const bool stager   = (w2 < wpc);
    const bool computer = (lane < S * S);
    const int slotbase = r4 * PITCH + 2 * w2;
    const float* __restrict__ gb =
        images + (size_t)(n * NC + c0) * PLANE + y1 * NW + x1a + 2 * w2;
    float* __restrict__ L0 = &lds[wid][0][0];
    float* __restrict__ L1 = &lds[wid][1][0];

    float m[8] = {NINF, NINF, NINF, NINF, NINF, NINF, NINF, NINF};
    // sh class -> (Q rows-rounds, A); sw class -> B. Q*4 >= max sh of class.
    if (sh <= 7) {
        if (sw <= 7)       wave_body8<2,2,2>(gb,L0,L1,sh,r4,vb,dh,dw,slotbase,stager,computer,m);
        else if (sw <= 14) wave_body8<2,2,3>(gb,L0,L1,sh,r4,vb,dh,dw,slotbase,stager,computer,m);
        else               wave_body8<2,2,4>(gb,L0,L1,sh,r4,vb,dh,dw,slotbase,stager,computer,m);
    } else if (sh <= 14) {
        if (sw <= 7)       wave_body8<4,3,2>(gb,L0,L1,sh,r4,vb,dh,dw,slotbase,stager,computer,m);
        else if (sw <= 14) wave_body8<4,3,3>(gb,L0,L1,sh,r4,vb,dh,dw,slotbase,stager,computer,m);
        else               wave_body8<4,3,4>(gb,L0,L1,sh,r4,vb,dh,dw,slotbase,stager,computer,m);
    } else {
        if (sw <= 7)       wave_body8<6,4,2>(gb,L0,L1,sh,r4,vb,dh,dw,slotbase,stager,computer,m);
        else if (sw <= 14) wave_body8<6,4,3>(gb,L0,L1,sh,r4,vb,dh,dw,slotbase,stager,computer,m);
        else               wave_body8<6,4,4>(gb,L0,L1,sh,r4,vb,dh,dw,slotbase,stager,computer,m);
    }

    // ---- stores: 392 contiguous floats per wave ----
    if (lane < S * S) {
#pragma unroll
        for (int p = 0; p < 8; ++p) {
            const size_t oi = (size_t)(r * NC + c0 + p) * (S * S) + lane;
            if (oi < (size_t)out_size) out[oi] = m[p];
        }
    }
}

extern "C" void kernel_launch(void* const* d_in, const int* in_sizes, int n_in,
                              void* d_out, int out_size, void* d_ws, size_t ws_size,
                              hipStream_t stream) {
    const float* images  = (const float*)d_in[0];
    const float* rois    = (const float*)d_in[1];
    const int*   roi_idx = (const int*)d_in[2];
    float* out = (float*)d_out;

    const int planes = out_size / (S * S);        // 65536
    const int groups = (planes + 7) / 8;          // 8192
    const int blocks = (groups + WPB - 1) / WPB;  // 2048
    roipool_kernel<<<blocks, 256, 0, stream>>>(images, rois, roi_idx, out, out_size);
}

// Round 15
// 75.841 us; speedup vs baseline: 1.0328x; 1.0328x over previous
//
#include <hip/hip_runtime.h>
#include <hip/hip_bf16.h>
#include <math.h>

// SlowROIPool: adaptive 7x7 max-pool over integer ROI crops.
// images [N=4,C=256,H=50,W=50] f32, rois [R=256,4] f32, roi_idx [R] i32.
// out [R,C,7,7] f32.
//
// R14 lesson: per-load exec masking + 8 planes/wave REGRESSED (branchy load
// clusters beat batched uniform ones; longer serial body per wave). Revert
// to the verified R13 structure; the only change vs R13 is a FINER Q-class
// ladder (7 sh-classes instead of 3) so the staging unroll covers sh with
// at most 3 duplicate row-slots (was up to 8): cuts the dominant L1
// line-transaction term + proportional DS writes, with zero new branches
// inside the body.
//   sh<=7->Q2A2, =8->Q2A3, <=12->Q3A3, <=14->Q4A3, <=16->Q4A4,
//   <=20->Q5A4, else Q6A4   (Q*4 >= sh; dh <= A per R13's verified SP map)
// Everything else byte-identical to R13: 4 planes/wave, float2 staging from
// even x1a ([x1a,x1a+32) always in-row), staging exec-masked to wpc pairs,
// unclamped const-delta taps + cndmask validity, single-buffered pairs
// (same-wave DS ops are in-order).
// All indices clamped: no global/LDS access can leave its buffer even under
// transiently-poisoned inputs.

#define S 7
#define NN 4
#define NC 256
#define NH 50
#define NW 50
#define PLANE (NH * NW)   // 2500
#define PITCH 34          // even (float2 align); > 31
#define PROWS 24          // padded rows
#define PBUF (PROWS * PITCH)  // 816 floats per plane buffer
#define WPB 4             // waves per block
#define NINF (-__builtin_huge_valf())

template <int A, int B>
__device__ __forceinline__ float tapmax(const float* __restrict__ L,
                                        int vb, int dh, int dw)
{
    float m = NINF;
#pragma unroll
    for (int a = 0; a < A; ++a) {
#pragma unroll
        for (int b = 0; b < B; ++b) {
            const bool valid = (a < dh) & (b < dw);   // dh<=A, dw<=B by class
            const float x = L[vb + a * PITCH + b];    // in padded buffer
            m = fmaxf(m, valid ? x : NINF);
        }
    }
    return m;
}

template <int Q, int A, int B>
__device__ __forceinline__ void wave_body(
    const float* __restrict__ gb,    // plane0 base + y1*NW + x1a + 2*w2
    float* __restrict__ L0, float* __restrict__ L1,
    int sh, int r4, int vb, int dh, int dw, int slotbase,
    bool stager, bool computer, float* __restrict__ m)
{
    float2 v[4][Q];
    if (stager) {                    // w2 < wpc: only useful bytes move
#pragma unroll
        for (int p = 0; p < 4; ++p) {
#pragma unroll
            for (int q = 0; q < Q; ++q) {
                const int rc = min(q * 4 + r4, sh - 1);   // dup rows: masked later
                v[p][q] = *(const float2*)(gb + (size_t)p * PLANE + rc * NW);
            }
        }
#pragma unroll
        for (int q = 0; q < Q; ++q) {
            const int slot = slotbase + q * 4 * PITCH;    // 8B-aligned
            *(float2*)(L0 + slot) = v[0][q];
            *(float2*)(L1 + slot) = v[1][q];
        }
    }
    if (computer) {
        m[0] = tapmax<A, B>(L0, vb, dh, dw);
        m[1] = tapmax<A, B>(L1, vb, dh, dw);
    }
    if (stager) {                    // same-wave DS in-order: WAR safe
#pragma unroll
        for (int q = 0; q < Q; ++q) {
            const int slot = slotbase + q * 4 * PITCH;
            *(float2*)(L0 + slot) = v[2][q];
            *(float2*)(L1 + slot) = v[3][q];
        }
    }
    if (computer) {
        m[2] = tapmax<A, B>(L0, vb, dh, dw);
        m[3] = tapmax<A, B>(L1, vb, dh, dw);
    }
}

__global__ __launch_bounds__(256, 4) void roipool_kernel(
    const float* __restrict__ images,
    const float* __restrict__ rois,
    const int* __restrict__ roi_idx,
    float* __restrict__ out,
    int out_size)
{
    __shared__ float lds[WPB][2][PBUF];   // 26.1 KB

    const int t    = threadIdx.x;
    const int wid  = __builtin_amdgcn_readfirstlane(t >> 6);
    const int lane = t & 63;
    const int grp  = blockIdx.x * WPB + wid;   // 4-plane group, < 16384
    int r = __builtin_amdgcn_readfirstlane(grp >> 6);   // 64 groups per ROI
    r = min(max(r, 0), 255);
    const int c0 = (grp & 63) * 4;

    // ---- box math: scalar, clamped (identity on sane inputs) ----
    const float rx1 = rois[4 * r + 0];
    const float ry1 = rois[4 * r + 1];
    const float rx2 = rois[4 * r + 2];
    const float ry2 = rois[4 * r + 3];
    int x1 = __builtin_amdgcn_readfirstlane((int)floorf(rx1 * (float)NW));
    int y1 = __builtin_amdgcn_readfirstlane((int)floorf(ry1 * (float)NH));
    int x2 = __builtin_amdgcn_readfirstlane((int)ceilf(rx2 * (float)NW));
    int y2 = __builtin_amdgcn_readfirstlane((int)ceilf(ry2 * (float)NH));
    x1 = min(max(x1, 0), NW - 1);
    y1 = min(max(y1, 0), NH - 1);
    x2 = min(max(x2, x1 + 1), NW);
    y2 = min(max(y2, y1 + 1), NH);
    const int sw = min(x2 - x1, 22);     // identity on real data (<= 22)
    const int sh = min(y2 - y1, 22);     // y1 + sh <= y2 <= NH: rows in-plane

    int n = __builtin_amdgcn_readfirstlane(roi_idx[r]);
    n = min(max(n, 0), NN - 1);

    // staged window: even start, [x1a, x1a+32) always inside the 50-col row
    const int x1a   = min(x1 & ~1, NW - 32);   // 0..18, even
    const int shift = x1 - x1a;                // 0..31; shift+sw <= 32

    // ---- per-lane bin (lanes 49..63 clone lane 48; masked in tap phase) ----
    const int l  = min(lane, S * S - 1);
    const int i  = l / S;
    const int j  = l - i * S;
    const int hs = (i * sh) / S;
    const int he = ((i + 1) * sh + S - 1) / S;
    const int ws = (j * sw) / S;
    const int we = ((j + 1) * sw + S - 1) / S;
    const int dh = he - hs;                    // <= SP(sh)
    const int dw = we - ws;                    // <= SP(sw)
    const int vb = hs * PITCH + ws + shift;    // max read 766 < 816 (padded)

    // ---- staging lane roles: 4 rows x 16 float2 cols, masked to wpc ----
    const int r4 = lane >> 4;                  // 0..3
    const int w2 = lane & 15;                  // 0..15
    const int wpc = (shift + sw + 1) >> 1;     // needed pairs, 1..16
    const bool stager   = (w2 < wpc);
    const bool computer = (lane < S * S);
    const int slotbase = r4 * PITCH + 2 * w2;
    const float* __restrict__ gb =
        images + (size_t)(n * NC + c0) * PLANE + y1 * NW + x1a + 2 * w2;
    float* __restrict__ L0 = &lds[wid][0][0];
    float* __restrict__ L1 = &lds[wid][1][0];

    float m[4] = {NINF, NINF, NINF, NINF};
    // Fine Q ladder: Q*4 >= sh with <=3 dup slots; A per verified SP map.
    if (sh <= 7) {
        if (sw <= 7)       wave_body<2,2,2>(gb,L0,L1,sh,r4,vb,dh,dw,slotbase,stager,computer,m);
        else if (sw <= 14) wave_body<2,2,3>(gb,L0,L1,sh,r4,vb,dh,dw,slotbase,stager,computer,m);
        else               wave_body<2,2,4>(gb,L0,L1,sh,r4,vb,dh,dw,slotbase,stager,computer,m);
    } else if (sh <= 8) {
        if (sw <= 7)       wave_body<2,3,2>(gb,L0,L1,sh,r4,vb,dh,dw,slotbase,stager,computer,m);
        else if (sw <= 14) wave_body<2,3,3>(gb,L0,L1,sh,r4,vb,dh,dw,slotbase,stager,computer,m);
        else               wave_body<2,3,4>(gb,L0,L1,sh,r4,vb,dh,dw,slotbase,stager,computer,m);
    } else if (sh <= 12) {
        if (sw <= 7)       wave_body<3,3,2>(gb,L0,L1,sh,r4,vb,dh,dw,slotbase,stager,computer,m);
        else if (sw <= 14) wave_body<3,3,3>(gb,L0,L1,sh,r4,vb,dh,dw,slotbase,stager,computer,m);
        else               wave_body<3,3,4>(gb,L0,L1,sh,r4,vb,dh,dw,slotbase,stager,computer,m);
    } else if (sh <= 14) {
        if (sw <= 7)       wave_body<4,3,2>(gb,L0,L1,sh,r4,vb,dh,dw,slotbase,stager,computer,m);
        else if (sw <= 14) wave_body<4,3,3>(gb,L0,L1,sh,r4,vb,dh,dw,slotbase,stager,computer,m);
        else               wave_body<4,3,4>(gb,L0,L1,sh,r4,vb,dh,dw,slotbase,stager,computer,m);
    } else if (sh <= 16) {
        if (sw <= 7)       wave_body<4,4,2>(gb,L0,L1,sh,r4,vb,dh,dw,slotbase,stager,computer,m);
        else if (sw <= 14) wave_body<4,4,3>(gb,L0,L1,sh,r4,vb,dh,dw,slotbase,stager,computer,m);
        else               wave_body<4,4,4>(gb,L0,L1,sh,r4,vb,dh,dw,slotbase,stager,computer,m);
    } else if (sh <= 20) {
        if (sw <= 7)       wave_body<5,4,2>(gb,L0,L1,sh,r4,vb,dh,dw,slotbase,stager,computer,m);
        else if (sw <= 14) wave_body<5,4,3>(gb,L0,L1,sh,r4,vb,dh,dw,slotbase,stager,computer,m);
        else               wave_body<5,4,4>(gb,L0,L1,sh,r4,vb,dh,dw,slotbase,stager,computer,m);
    } else {
        if (sw <= 7)       wave_body<6,4,2>(gb,L0,L1,sh,r4,vb,dh,dw,slotbase,stager,computer,m);
        else if (sw <= 14) wave_body<6,4,3>(gb,L0,L1,sh,r4,vb,dh,dw,slotbase,stager,computer,m);
        else               wave_body<6,4,4>(gb,L0,L1,sh,r4,vb,dh,dw,slotbase,stager,computer,m);
    }

    // ---- stores: 196 contiguous floats per wave ----
    if (lane < S * S) {
#pragma unroll
        for (int p = 0; p < 4; ++p) {
            const size_t oi = (size_t)(r * NC + c0 + p) * (S * S) + lane;
            if (oi < (size_t)out_size) out[oi] = m[p];
        }
    }
}

extern "C" void kernel_launch(void* const* d_in, const int* in_sizes, int n_in,
                              void* d_out, int out_size, void* d_ws, size_t ws_size,
                              hipStream_t stream) {
    const float* images  = (const float*)d_in[0];
    const float* rois    = (const float*)d_in[1];
    const int*   roi_idx = (const int*)d_in[2];
    float* out = (float*)d_out;

    const int planes = out_size / (S * S);        // 65536
    const int groups = (planes + 3) / 4;          // 16384
    const int blocks = (groups + WPB - 1) / WPB;  // 4096
    roipool_kernel<<<blocks, 256, 0, stream>>>(images, rois, roi_idx, out, out_size);
}